// Round 2
// baseline (494.381 us; speedup 1.0000x reference)
//
#include <hip/hip_runtime.h>
#include <stdint.h>

typedef _Float16 f16_t;
typedef _Float16 f16x4 __attribute__((ext_vector_type(4)));
typedef _Float16 f16x8 __attribute__((ext_vector_type(8)));
typedef float f32x4 __attribute__((ext_vector_type(4)));

// ---------------------------------------------------------------------------
// async global->LDS, 16B per lane. LDS dest is wave-uniform base + lane*16.
// ---------------------------------------------------------------------------
__device__ __forceinline__ void async16(const void* g, void* lds) {
    typedef __attribute__((address_space(3))) void lds_void;
    typedef __attribute__((address_space(1))) void glb_void;
    lds_void* l = (lds_void*)(unsigned int)(unsigned long long)lds;
    glb_void* gp = (glb_void*)(unsigned long long)g;
    __builtin_amdgcn_global_load_lds(gp, l, 16, 0, 0);
}

// ---------------------------------------------------------------------------
// fp32 -> fp16 elementwise (weights)
// ---------------------------------------------------------------------------
__global__ void cvt_f32_f16(const float* __restrict__ in, f16_t* __restrict__ out, int n) {
    int i = blockIdx.x * 256 + threadIdx.x;
    if (i < n) out[i] = (f16_t)in[i];
}

// ---------------------------------------------------------------------------
// Transpose + convert to fp16.  in: [R][S] per batch  ->  out: [S][R]
// TIN = float or f16. 32x32 tiles via padded LDS, 256 threads.
// ---------------------------------------------------------------------------
template <typename TIN>
__global__ void transpose_cvt(const TIN* __restrict__ in, f16_t* __restrict__ out,
                              int R, int S, long long inStride, long long outStride) {
    __shared__ float tile[32][33];
    const int b = blockIdx.z;
    const TIN* ip = in + (long long)b * inStride;
    f16_t* op = out + (long long)b * outStride;
    const int s0 = blockIdx.x * 32;
    const int r0 = blockIdx.y * 32;
    const int t = threadIdx.x;
    const int lr = t >> 3;
    const int lc = (t & 7) * 4;

    const TIN* src = ip + (long long)(r0 + lr) * S + s0 + lc;
    float v0, v1, v2, v3;
    if (sizeof(TIN) == 4) {
        float4 v = *(const float4*)src;
        v0 = v.x; v1 = v.y; v2 = v.z; v3 = v.w;
    } else {
        f16x4 v = *(const f16x4*)src;
        v0 = (float)v[0]; v1 = (float)v[1]; v2 = (float)v[2]; v3 = (float)v[3];
    }
    tile[lr][lc + 0] = v0;
    tile[lr][lc + 1] = v1;
    tile[lr][lc + 2] = v2;
    tile[lr][lc + 3] = v3;
    __syncthreads();

    const int sr = t >> 3;
    const int rc = (t & 7) * 4;
    f16x4 o;
    o[0] = (f16_t)tile[rc + 0][sr];
    o[1] = (f16_t)tile[rc + 1][sr];
    o[2] = (f16_t)tile[rc + 2][sr];
    o[3] = (f16_t)tile[rc + 3][sr];
    *(f16x4*)(op + (long long)(s0 + sr) * R + r0 + rc) = o;
}

// ---------------------------------------------------------------------------
// bt-GEMM:  C[m,n] = sum_k A[m,k] * Bt[n,k]     (both K-contiguous, fp16)
// BK=32, 16x16x32 f16 MFMA, 256 threads = 4 waves (WM x WN), TM x TN tiles/wave.
// MODE 0: store f16 C.  MODE 1: store fp32 C.  MODE 2: f16 gamma*acc + resid.
// ---------------------------------------------------------------------------
template <int BM, int BN, int TM, int TN, int WM, int WN, int MODE>
__global__ __launch_bounds__(256, 2)
void gemm_bt(const f16_t* __restrict__ A, const f16_t* __restrict__ B,
             void* __restrict__ C, const f16_t* __restrict__ resid,
             const float* __restrict__ gamma,
             int M, int N, int K,
             long long strideA, long long strideB, long long strideC) {
    constexpr int BK = 32;
    __shared__ __align__(16) f16_t As[BM * BK];
    __shared__ __align__(16) f16_t Bs[BN * BK];

    const int tid = threadIdx.x;
    const int wave = tid >> 6;
    const int lane = tid & 63;
    const int wm = wave / WN;
    const int wn = wave % WN;
    const int l16 = lane & 15;
    const int l4 = lane >> 4;

    const long long zb = blockIdx.z;
    const f16_t* Ab = A + zb * strideA + (long long)blockIdx.y * BM * K;
    const f16_t* Bb = B + zb * strideB + (long long)blockIdx.x * BN * K;

    f32x4 zero = {0.f, 0.f, 0.f, 0.f};
    f32x4 acc[TM][TN];
#pragma unroll
    for (int i = 0; i < TM; ++i)
#pragma unroll
        for (int j = 0; j < TN; ++j) acc[i][j] = zero;

    for (int k0 = 0; k0 < K; k0 += BK) {
        // stage A tile: BM rows x 64B, 16B segs, seg id follows lane order
#pragma unroll
        for (int r = 0; r < (BM * 4) / 256; ++r) {
            int seg = r * 256 + tid;
            const f16_t* g = Ab + (long long)(seg >> 2) * K + k0 + (seg & 3) * 8;
            async16(g, &As[(r * 256 + wave * 64) * 8]);
        }
#pragma unroll
        for (int r = 0; r < (BN * 4) / 256; ++r) {
            int seg = r * 256 + tid;
            const f16_t* g = Bb + (long long)(seg >> 2) * K + k0 + (seg & 3) * 8;
            async16(g, &Bs[(r * 256 + wave * 64) * 8]);
        }
        __syncthreads();

        f16x8 af[TM], bfr[TN];
#pragma unroll
        for (int i = 0; i < TM; ++i)
            af[i] = *(const f16x8*)&As[((wm * TM + i) * 16 + l16) * BK + l4 * 8];
#pragma unroll
        for (int j = 0; j < TN; ++j)
            bfr[j] = *(const f16x8*)&Bs[((wn * TN + j) * 16 + l16) * BK + l4 * 8];
#pragma unroll
        for (int i = 0; i < TM; ++i)
#pragma unroll
            for (int j = 0; j < TN; ++j)
                acc[i][j] = __builtin_amdgcn_mfma_f32_16x16x32_f16(af[i], bfr[j], acc[i][j], 0, 0, 0);
        __syncthreads();
    }

    // epilogue: C/D layout col = lane&15, row = (lane>>4)*4 + reg
    const int row0 = blockIdx.y * BM + wm * TM * 16;
    const int col0 = blockIdx.x * BN + wn * TN * 16;
    float g = (MODE == 2) ? gamma[0] : 0.f;
#pragma unroll
    for (int i = 0; i < TM; ++i) {
#pragma unroll
        for (int j = 0; j < TN; ++j) {
#pragma unroll
            for (int r = 0; r < 4; ++r) {
                int row = row0 + i * 16 + l4 * 4 + r;
                int col = col0 + j * 16 + l16;
                long long idx = zb * strideC + (long long)row * N + col;
                float v = acc[i][j][r];
                if (MODE == 0) {
                    ((f16_t*)C)[idx] = (f16_t)v;
                } else if (MODE == 1) {
                    ((float*)C)[idx] = v;
                } else {
                    float im = (float)resid[idx];
                    ((f16_t*)C)[idx] = (f16_t)(g * v + im);
                }
            }
        }
    }
}

// ---------------------------------------------------------------------------
// softmax over rows of 256 fp32 -> fp16.  One wave per row, 4 rows per block.
// ---------------------------------------------------------------------------
__global__ void softmax256(const float* __restrict__ attn, f16_t* __restrict__ out) {
    const int row = blockIdx.x * 4 + (threadIdx.x >> 6);
    const int lane = threadIdx.x & 63;
    const float4 v = *(const float4*)(attn + (long long)row * 256 + lane * 4);
    float m = fmaxf(fmaxf(v.x, v.y), fmaxf(v.z, v.w));
#pragma unroll
    for (int off = 32; off > 0; off >>= 1) m = fmaxf(m, __shfl_xor(m, off, 64));
    float e0 = __expf(v.x - m), e1 = __expf(v.y - m);
    float e2 = __expf(v.z - m), e3 = __expf(v.w - m);
    float s = e0 + e1 + e2 + e3;
#pragma unroll
    for (int off = 32; off > 0; off >>= 1) s += __shfl_xor(s, off, 64);
    const float inv = 1.0f / s;
    f16x4 o;
    o[0] = (f16_t)(e0 * inv);
    o[1] = (f16_t)(e1 * inv);
    o[2] = (f16_t)(e2 * inv);
    o[3] = (f16_t)(e3 * inv);
    *(f16x4*)(out + (long long)row * 256 + lane * 4) = o;
}

// ---------------------------------------------------------------------------
// Orchestration
// ---------------------------------------------------------------------------
extern "C" void kernel_launch(void* const* d_in, const int* in_sizes, int n_in,
                              void* d_out, int out_size, void* d_ws, size_t ws_size,
                              hipStream_t stream) {
    (void)in_sizes; (void)n_in; (void)out_size; (void)ws_size;

    const float* x1 = (const float*)d_in[0];     // [16,512,64,64]
    const float* x2 = (const float*)d_in[1];     // [16,320,64,64]
    const float* w_img = (const float*)d_in[2];  // [256,512]
    const float* w_txt = (const float*)d_in[3];  // [256,320]
    const float* w_out = (const float*)d_in[4];  // [512,256]
    const float* gamma = (const float*)d_in[5];  // [1]

    constexpr int B = 16, C1 = 512, C2 = 320, C = 256, N = 4096, OC = 512;

    // ws layout (bytes): needs ~104.7 MiB
    char* ws = (char*)d_ws;
    f16_t* wib = (f16_t*)(ws + 0);          // 256*512*2   = 262144
    f16_t* wtb = (f16_t*)(ws + 262144);     // 256*320*2   = 163840
    f16_t* wob = (f16_t*)(ws + 425984);     // 512*256*2   = 262144
    f16_t* img = (f16_t*)(ws + 688128);     // 16*256*4096*2 = 33554432
    f16_t* x2t = (f16_t*)(ws + 34242560);   // 16*4096*320*2 = 41943040
    f16_t* kvT = x2t;                       // reuse (x2t dead after GEMM2)
    f16_t* yT  = (f16_t*)(ws + 76185600);   // 33554432 -> ends 109740032

    // d_out used as scratch before the final GEMM overwrites all of it
    char* oc = (char*)d_out;
    f16_t* x1t   = (f16_t*)(oc);             // [0, 67108864)
    f16_t* kv    = (f16_t*)(oc);             // [0, 33554432)  after x1t dead
    f16_t* y     = (f16_t*)(oc + 67108864);  // 33554432
    float* attn  = (float*)(oc + 100663296); // 4194304
    f16_t* attns = (f16_t*)(oc + 104857600); // 2097152 -> ends 106954752

    // 1. weights -> f16
    cvt_f32_f16<<<(C * C1 + 255) / 256, 256, 0, stream>>>(w_img, wib, C * C1);
    cvt_f32_f16<<<(C * C2 + 255) / 256, 256, 0, stream>>>(w_txt, wtb, C * C2);
    cvt_f32_f16<<<(OC * C + 255) / 256, 256, 0, stream>>>(w_out, wob, OC * C);

    // 2. x1 [C1,N] -> x1t [N,C1] f16 ; x2 -> x2t [N,C2]
    transpose_cvt<float><<<dim3(N / 32, C1 / 32, B), 256, 0, stream>>>(
        x1, x1t, C1, N, (long long)C1 * N, (long long)N * C1);
    transpose_cvt<float><<<dim3(N / 32, C2 / 32, B), 256, 0, stream>>>(
        x2, x2t, C2, N, (long long)C2 * N, (long long)N * C2);

    // 3. img = w_img * x1  -> [C,N] f16    (M=256,N=4096,K=512)
    gemm_bt<128, 128, 4, 4, 2, 2, 0><<<dim3(N / 128, C / 128, B), 256, 0, stream>>>(
        wib, x1t, img, nullptr, nullptr, C, N, C1,
        0LL, (long long)N * C1, (long long)C * N);

    // 4. kv = w_txt * x2  -> [C,N] f16     (M=256,N=4096,K=320)
    gemm_bt<128, 128, 4, 4, 2, 2, 0><<<dim3(N / 128, C / 128, B), 256, 0, stream>>>(
        wtb, x2t, kv, nullptr, nullptr, C, N, C2,
        0LL, (long long)N * C2, (long long)C * N);

    // 5. kvT [N,C]
    transpose_cvt<f16_t><<<dim3(N / 32, C / 32, B), 256, 0, stream>>>(
        kv, kvT, C, N, (long long)C * N, (long long)N * C);

    // 6. attn = img * kv^T (over spatial)  [C,C] fp32  (M=N=256,K=4096)
    gemm_bt<64, 64, 2, 2, 2, 2, 1><<<dim3(C / 64, C / 64, B), 256, 0, stream>>>(
        img, kv, attn, nullptr, nullptr, C, C, N,
        (long long)C * N, (long long)C * N, (long long)C * C);

    // 7. softmax rows -> f16
    softmax256<<<(B * C) / 4, 256, 0, stream>>>(attn, attns);

    // 8. y = gamma * (attn * kv) + img  -> [C,N] f16  (M=256,N=4096,K=256)
    gemm_bt<128, 128, 4, 4, 2, 2, 2><<<dim3(N / 128, C / 128, B), 256, 0, stream>>>(
        attns, kvT, y, img, gamma, C, N, C,
        (long long)C * C, (long long)N * C, (long long)C * N);

    // 9. yT [N,C]
    transpose_cvt<f16_t><<<dim3(N / 32, C / 32, B), 256, 0, stream>>>(
        y, yT, C, N, (long long)C * N, (long long)N * C);

    // 10. out = w_out * y  -> [OC,N] fp32   (M=512,N=4096,K=256)
    gemm_bt<128, 128, 4, 4, 2, 2, 1><<<dim3(N / 128, OC / 128, B), 256, 0, stream>>>(
        wob, yT, (float*)d_out, nullptr, nullptr, OC, N, C,
        0LL, (long long)N * C, (long long)OC * N);
}